// Round 1
// baseline (791.083 us; speedup 1.0000x reference)
//
#include <hip/hip_runtime.h>
#include <hip/hip_bf16.h>
#include <math.h>

#define N_NODES 50000
#define N_EDGES 800000
#define ETOT    (N_EDGES + N_NODES)
#define FDIM    256
#define SLOPE   0.2f

// ---------------------------------------------------------------------------
// CSR build (dst-indexed, includes self loops). Rebuilt every call (no state).
// ---------------------------------------------------------------------------
__global__ void init_counts(int* __restrict__ counts) {
    int i = blockIdx.x * blockDim.x + threadIdx.x;
    if (i < N_NODES) counts[i] = 1;   // self loop contributes 1 in-edge
}

__global__ void count_edges(const int* __restrict__ dst, int* __restrict__ counts) {
    int i = blockIdx.x * blockDim.x + threadIdx.x;
    if (i < N_EDGES) atomicAdd(&counts[dst[i]], 1);
}

// Block-local inclusive scan over 1024 elements (256 threads x 4).
__global__ void scan1(const int* __restrict__ counts, int* __restrict__ partial,
                      int* __restrict__ blockSums) {
    __shared__ int wsum[4];
    int b = blockIdx.x, t = threadIdx.x;
    int base = b * 1024;
    int i0 = base + t * 4;
    int v[4];
#pragma unroll
    for (int u = 0; u < 4; u++) { int i = i0 + u; v[u] = (i < N_NODES) ? counts[i] : 0; }
    v[1] += v[0]; v[2] += v[1]; v[3] += v[2];
    int lane = t & 63, wid = t >> 6;
    int incl = v[3];
#pragma unroll
    for (int d = 1; d < 64; d <<= 1) {
        int o = __shfl_up(incl, d, 64);
        if (lane >= d) incl += o;
    }
    if (lane == 63) wsum[wid] = incl;
    __syncthreads();
    int woff = 0;
#pragma unroll
    for (int w = 0; w < 4; w++) if (w < wid) woff += wsum[w];
    int texcl = woff + incl - v[3];
#pragma unroll
    for (int u = 0; u < 4; u++) { int i = i0 + u; if (i < N_NODES) partial[i] = texcl + v[u]; }
    if (t == 255) blockSums[b] = woff + incl;
}

__global__ void scan2(int* __restrict__ blockSums, int nb) {
    int t = threadIdx.x;
    int v = (t < nb) ? blockSums[t] : 0;
    int incl = v;
#pragma unroll
    for (int d = 1; d < 64; d <<= 1) {
        int o = __shfl_up(incl, d, 64);
        if (t >= d) incl += o;
    }
    if (t < nb) blockSums[t] = incl - v;   // exclusive block offsets
}

__global__ void scan3(const int* __restrict__ partial, const int* __restrict__ blockOffs,
                      int* __restrict__ row_ptr, int* __restrict__ cursor) {
    int b = blockIdx.x, t = threadIdx.x;
    int base = b * 1024;
    int off = blockOffs[b];
#pragma unroll
    for (int u = 0; u < 4; u++) {
        int i = base + t + u * 256;
        if (i < N_NODES) {
            row_ptr[i + 1] = off + partial[i];
            cursor[i]      = off + ((i == base) ? 0 : partial[i - 1]);
        }
    }
    if (b == 0 && t == 0) row_ptr[0] = 0;
}

__global__ void scatter_edges(const int* __restrict__ src, const int* __restrict__ dst,
                              int* __restrict__ cursor, int* __restrict__ col_src) {
    int i = blockIdx.x * blockDim.x + threadIdx.x;
    if (i >= ETOT) return;
    int s, d;
    if (i < N_EDGES) { s = src[i]; d = dst[i]; }
    else             { s = i - N_EDGES; d = s; }
    int p = atomicAdd(&cursor[d], 1);
    col_src[p] = s;
}

// ---------------------------------------------------------------------------
// fp32 GEMM: C[M,256] = A[M,256] @ B[256,256].  64x64 tile, 4x4 per thread.
// ---------------------------------------------------------------------------
__global__ __launch_bounds__(256) void gemm256(const float* __restrict__ A,
                                               const float* __restrict__ B,
                                               float* __restrict__ C, int M) {
    __shared__ float As[16][68];   // [k][m], pad keeps 16B alignment (68*4=272)
    __shared__ float Bs[16][68];   // [k][n]
    int t = threadIdx.x;
    int bn = blockIdx.x, bm = blockIdx.y;
    int row0 = bm * 64, col0 = bn * 64;
    int tx = t & 15, ty = t >> 4;
    int arow = t >> 2, acol = (t & 3) << 2;   // A tile: 64 rows x 16 k
    int brow = t >> 4, bcol = (t & 15) << 2;  // B tile: 16 k x 64 cols
    float acc[4][4] = {{0.f}};

    for (int k0 = 0; k0 < 256; k0 += 16) {
        float4 av = make_float4(0.f, 0.f, 0.f, 0.f);
        int gr = row0 + arow;
        if (gr < M) av = *(const float4*)(A + (size_t)gr * 256 + k0 + acol);
        As[acol + 0][arow] = av.x;
        As[acol + 1][arow] = av.y;
        As[acol + 2][arow] = av.z;
        As[acol + 3][arow] = av.w;
        float4 bv = *(const float4*)(B + (size_t)(k0 + brow) * 256 + col0 + bcol);
        *(float4*)&Bs[brow][bcol] = bv;
        __syncthreads();
#pragma unroll
        for (int kk = 0; kk < 16; kk++) {
            float4 ra = *(const float4*)&As[kk][ty << 2];
            float4 rb = *(const float4*)&Bs[kk][tx << 2];
            float a_[4] = {ra.x, ra.y, ra.z, ra.w};
            float b_[4] = {rb.x, rb.y, rb.z, rb.w};
#pragma unroll
            for (int i = 0; i < 4; i++)
#pragma unroll
                for (int j = 0; j < 4; j++)
                    acc[i][j] = fmaf(a_[i], b_[j], acc[i][j]);
        }
        __syncthreads();
    }
#pragma unroll
    for (int i = 0; i < 4; i++) {
        int r = row0 + (ty << 2) + i;
        if (r < M) {
            float4 o = make_float4(acc[i][0], acc[i][1], acc[i][2], acc[i][3]);
            *(float4*)(C + (size_t)r * 256 + col0 + (tx << 2)) = o;
        }
    }
}

// ---------------------------------------------------------------------------
// alpha_s / alpha_d:  per node, dot of xW row with a_src / a_dst.
// heads==4: per-wave (64-chunk) reduce; heads==1: full-row reduce.
// ---------------------------------------------------------------------------
__global__ __launch_bounds__(256) void alpha_kernel(const float* __restrict__ xW,
                                                    const float* __restrict__ a_src,
                                                    const float* __restrict__ a_dst,
                                                    float* __restrict__ aS,
                                                    float* __restrict__ aD, int heads) {
    int v = blockIdx.x, t = threadIdx.x;
    float x = xW[(size_t)v * 256 + t];
    float ps = x * a_src[t];
    float pd = x * a_dst[t];
#pragma unroll
    for (int d = 32; d; d >>= 1) {
        ps += __shfl_down(ps, d, 64);
        pd += __shfl_down(pd, d, 64);
    }
    int lane = t & 63, wid = t >> 6;
    if (heads == 4) {
        if (lane == 0) { aS[v * 4 + wid] = ps; aD[v * 4 + wid] = pd; }
    } else {
        __shared__ float sp[4], sd[4];
        if (lane == 0) { sp[wid] = ps; sd[wid] = pd; }
        __syncthreads();
        if (t == 0) {
            aS[v] = sp[0] + sp[1] + sp[2] + sp[3];
            aD[v] = sd[0] + sd[1] + sd[2] + sd[3];
        }
    }
}

// ---------------------------------------------------------------------------
// Per-node segment softmax + weighted aggregation over in-edges (CSR).
// One 256-thread block per node; thread t owns output feature t.
// ---------------------------------------------------------------------------
template <int HEADS, bool ELU>
__global__ __launch_bounds__(256) void gat_aggregate(const float* __restrict__ xW,
                                                     const float* __restrict__ aS,
                                                     const float* __restrict__ aD,
                                                     const int* __restrict__ row_ptr,
                                                     const int* __restrict__ col_src,
                                                     const float* __restrict__ bias,
                                                     float* __restrict__ out) {
    int v = blockIdx.x, t = threadIdx.x;
    int lane = t & 63, wid = t >> 6;
    int head = (HEADS == 4) ? wid : 0;
    float adv = aD[v * HEADS + head];
    int beg = row_ptr[v], end = row_ptr[v + 1];
    __shared__ float red[4];

    // ---- pass 1: segment max ----
    float m = -3.4e38f;
    if (HEADS == 4) {
        for (int j = beg + lane; j < end; j += 64) {
            int s = col_src[j];
            float e = aS[s * 4 + head] + adv;
            e = (e > 0.f) ? e : SLOPE * e;
            m = fmaxf(m, e);
        }
#pragma unroll
        for (int d = 32; d; d >>= 1) m = fmaxf(m, __shfl_xor(m, d, 64));
    } else {
        for (int j = beg + t; j < end; j += 256) {
            int s = col_src[j];
            float e = aS[s] + adv;
            e = (e > 0.f) ? e : SLOPE * e;
            m = fmaxf(m, e);
        }
#pragma unroll
        for (int d = 32; d; d >>= 1) m = fmaxf(m, __shfl_xor(m, d, 64));
        if (lane == 0) red[wid] = m;
        __syncthreads();
        m = fmaxf(fmaxf(red[0], red[1]), fmaxf(red[2], red[3]));
        __syncthreads();
    }

    // ---- pass 2: z = sum exp(e - m) ----
    float z = 0.f;
    if (HEADS == 4) {
        for (int j = beg + lane; j < end; j += 64) {
            int s = col_src[j];
            float e = aS[s * 4 + head] + adv;
            e = (e > 0.f) ? e : SLOPE * e;
            z += __expf(e - m);
        }
#pragma unroll
        for (int d = 32; d; d >>= 1) z += __shfl_xor(z, d, 64);
    } else {
        for (int j = beg + t; j < end; j += 256) {
            int s = col_src[j];
            float e = aS[s] + adv;
            e = (e > 0.f) ? e : SLOPE * e;
            z += __expf(e - m);
        }
#pragma unroll
        for (int d = 32; d; d >>= 1) z += __shfl_xor(z, d, 64);
        if (lane == 0) red[wid] = z;
        __syncthreads();
        z = red[0] + red[1] + red[2] + red[3];
    }

    // ---- pass 3: weighted gather-accumulate ----
    float acc = 0.f;
    for (int j = beg; j < end; ++j) {
        int s = col_src[j];
        float e = aS[s * HEADS + head] + adv;
        e = (e > 0.f) ? e : SLOPE * e;
        float wgt = __expf(e - m);
        acc = fmaf(wgt, xW[(size_t)s * 256 + t], acc);
    }
    float r = acc / z + bias[t];
    if (ELU) r = (r > 0.f) ? r : expm1f(r);
    out[(size_t)v * 256 + t] = r;
}

// ---------------------------------------------------------------------------
extern "C" void kernel_launch(void* const* d_in, const int* in_sizes, int n_in,
                              void* d_out, int out_size, void* d_ws, size_t ws_size,
                              hipStream_t stream) {
    const float* x   = (const float*)d_in[0];
    const int*   ei  = (const int*)d_in[1];
    const float* W1  = (const float*)d_in[2];
    const float* as1 = (const float*)d_in[3];
    const float* ad1 = (const float*)d_in[4];
    const float* b1  = (const float*)d_in[5];
    const float* W2  = (const float*)d_in[6];
    const float* as2 = (const float*)d_in[7];
    const float* ad2 = (const float*)d_in[8];
    const float* b2  = (const float*)d_in[9];
    float* out = (float*)d_out;

    const int* src = ei;
    const int* dst = ei + N_EDGES;

    // workspace carve-up (all offsets 16B-aligned)
    char* w = (char*)d_ws;
    float* xW = (float*)w;  w += (size_t)N_NODES * 256 * 4;        // 51.2 MB
    float* h  = (float*)w;  w += (size_t)N_NODES * 256 * 4;        // 51.2 MB
    float* aS = (float*)w;  w += (size_t)N_NODES * 4 * 4;          // 0.8 MB
    float* aD = (float*)w;  w += (size_t)N_NODES * 4 * 4;          // 0.8 MB
    int* row_ptr = (int*)w; w += (((size_t)(N_NODES + 1) * 4 + 255) / 256) * 256;
    int* counts  = (int*)w; w += (((size_t)N_NODES * 4 + 255) / 256) * 256;
    int* cursor  = (int*)w; w += (((size_t)N_NODES * 4 + 255) / 256) * 256;
    int* partial = (int*)w; w += (((size_t)N_NODES * 4 + 255) / 256) * 256;
    int* bsums   = (int*)w; w += 256;
    int* col_src = (int*)w; w += (size_t)ETOT * 4;                 // 3.4 MB

    int nb = (N_NODES + 1023) / 1024;   // 49

    // --- CSR build ---
    init_counts<<<(N_NODES + 255) / 256, 256, 0, stream>>>(counts);
    count_edges<<<(N_EDGES + 255) / 256, 256, 0, stream>>>(dst, counts);
    scan1<<<nb, 256, 0, stream>>>(counts, partial, bsums);
    scan2<<<1, 64, 0, stream>>>(bsums, nb);
    scan3<<<nb, 256, 0, stream>>>(partial, bsums, row_ptr, cursor);
    scatter_edges<<<(ETOT + 255) / 256, 256, 0, stream>>>(src, dst, cursor, col_src);

    dim3 ggrid(4, (N_NODES + 63) / 64);

    // --- layer 1 (H=4, C=64) ---
    gemm256<<<ggrid, 256, 0, stream>>>(x, W1, xW, N_NODES);
    alpha_kernel<<<N_NODES, 256, 0, stream>>>(xW, as1, ad1, aS, aD, 4);
    gat_aggregate<4, true><<<N_NODES, 256, 0, stream>>>(xW, aS, aD, row_ptr, col_src, b1, h);

    // --- layer 2 (H=1, C=256) ---
    gemm256<<<ggrid, 256, 0, stream>>>(h, W2, xW, N_NODES);
    alpha_kernel<<<N_NODES, 256, 0, stream>>>(xW, as2, ad2, aS, aD, 1);
    gat_aggregate<1, false><<<N_NODES, 256, 0, stream>>>(xW, aS, aD, row_ptr, col_src, b2, out);
}

// Round 2
// 593.991 us; speedup vs baseline: 1.3318x; 1.3318x over previous
//
#include <hip/hip_runtime.h>
#include <hip/hip_bf16.h>
#include <math.h>

#define N_NODES 50000
#define N_EDGES 800000
#define ETOT    (N_EDGES + N_NODES)
#define FDIM    256
#define SLOPE   0.2f

// ---------------------------------------------------------------------------
// CSR build (dst-indexed, includes self loops). Rebuilt every call (no state).
// ---------------------------------------------------------------------------
__global__ void init_counts(int* __restrict__ counts) {
    int i = blockIdx.x * blockDim.x + threadIdx.x;
    if (i < N_NODES) counts[i] = 1;   // self loop contributes 1 in-edge
}

__global__ void count_edges(const int* __restrict__ dst, int* __restrict__ counts) {
    int i = blockIdx.x * blockDim.x + threadIdx.x;
    if (i < N_EDGES) atomicAdd(&counts[dst[i]], 1);
}

// Block-local inclusive scan over 1024 elements (256 threads x 4).
__global__ void scan1(const int* __restrict__ counts, int* __restrict__ partial,
                      int* __restrict__ blockSums) {
    __shared__ int wsum[4];
    int b = blockIdx.x, t = threadIdx.x;
    int base = b * 1024;
    int i0 = base + t * 4;
    int v[4];
#pragma unroll
    for (int u = 0; u < 4; u++) { int i = i0 + u; v[u] = (i < N_NODES) ? counts[i] : 0; }
    v[1] += v[0]; v[2] += v[1]; v[3] += v[2];
    int lane = t & 63, wid = t >> 6;
    int incl = v[3];
#pragma unroll
    for (int d = 1; d < 64; d <<= 1) {
        int o = __shfl_up(incl, d, 64);
        if (lane >= d) incl += o;
    }
    if (lane == 63) wsum[wid] = incl;
    __syncthreads();
    int woff = 0;
#pragma unroll
    for (int w = 0; w < 4; w++) if (w < wid) woff += wsum[w];
    int texcl = woff + incl - v[3];
#pragma unroll
    for (int u = 0; u < 4; u++) { int i = i0 + u; if (i < N_NODES) partial[i] = texcl + v[u]; }
    if (t == 255) blockSums[b] = woff + incl;
}

__global__ void scan2(int* __restrict__ blockSums, int nb) {
    int t = threadIdx.x;
    int v = (t < nb) ? blockSums[t] : 0;
    int incl = v;
#pragma unroll
    for (int d = 1; d < 64; d <<= 1) {
        int o = __shfl_up(incl, d, 64);
        if (t >= d) incl += o;
    }
    if (t < nb) blockSums[t] = incl - v;   // exclusive block offsets
}

__global__ void scan3(const int* __restrict__ partial, const int* __restrict__ blockOffs,
                      int* __restrict__ row_ptr, int* __restrict__ cursor) {
    int b = blockIdx.x, t = threadIdx.x;
    int base = b * 1024;
    int off = blockOffs[b];
#pragma unroll
    for (int u = 0; u < 4; u++) {
        int i = base + t + u * 256;
        if (i < N_NODES) {
            row_ptr[i + 1] = off + partial[i];
            cursor[i]      = off + ((i == base) ? 0 : partial[i - 1]);
        }
    }
    if (b == 0 && t == 0) row_ptr[0] = 0;
}

__global__ void scatter_edges(const int* __restrict__ src, const int* __restrict__ dst,
                              int* __restrict__ cursor, int* __restrict__ col_src) {
    int i = blockIdx.x * blockDim.x + threadIdx.x;
    if (i >= ETOT) return;
    int s, d;
    if (i < N_EDGES) { s = src[i]; d = dst[i]; }
    else             { s = i - N_EDGES; d = s; }
    int p = atomicAdd(&cursor[d], 1);
    col_src[p] = s;
}

// ---------------------------------------------------------------------------
// fp32 GEMM: C[M,256] = A[M,256] @ B[256,256].  64x64 tile, 4x4 per thread.
// ---------------------------------------------------------------------------
__global__ __launch_bounds__(256) void gemm256(const float* __restrict__ A,
                                               const float* __restrict__ B,
                                               float* __restrict__ C, int M) {
    __shared__ float As[16][68];
    __shared__ float Bs[16][68];
    int t = threadIdx.x;
    int bn = blockIdx.x, bm = blockIdx.y;
    int row0 = bm * 64, col0 = bn * 64;
    int tx = t & 15, ty = t >> 4;
    int arow = t >> 2, acol = (t & 3) << 2;
    int brow = t >> 4, bcol = (t & 15) << 2;
    float acc[4][4] = {{0.f}};

    for (int k0 = 0; k0 < 256; k0 += 16) {
        float4 av = make_float4(0.f, 0.f, 0.f, 0.f);
        int gr = row0 + arow;
        if (gr < M) av = *(const float4*)(A + (size_t)gr * 256 + k0 + acol);
        As[acol + 0][arow] = av.x;
        As[acol + 1][arow] = av.y;
        As[acol + 2][arow] = av.z;
        As[acol + 3][arow] = av.w;
        float4 bv = *(const float4*)(B + (size_t)(k0 + brow) * 256 + col0 + bcol);
        *(float4*)&Bs[brow][bcol] = bv;
        __syncthreads();
#pragma unroll
        for (int kk = 0; kk < 16; kk++) {
            float4 ra = *(const float4*)&As[kk][ty << 2];
            float4 rb = *(const float4*)&Bs[kk][tx << 2];
            float a_[4] = {ra.x, ra.y, ra.z, ra.w};
            float b_[4] = {rb.x, rb.y, rb.z, rb.w};
#pragma unroll
            for (int i = 0; i < 4; i++)
#pragma unroll
                for (int j = 0; j < 4; j++)
                    acc[i][j] = fmaf(a_[i], b_[j], acc[i][j]);
        }
        __syncthreads();
    }
#pragma unroll
    for (int i = 0; i < 4; i++) {
        int r = row0 + (ty << 2) + i;
        if (r < M) {
            float4 o = make_float4(acc[i][0], acc[i][1], acc[i][2], acc[i][3]);
            *(float4*)(C + (size_t)r * 256 + col0 + (tx << 2)) = o;
        }
    }
}

// ---------------------------------------------------------------------------
// alpha_s / alpha_d:  per node, dot of xW row with a_src / a_dst.
// ---------------------------------------------------------------------------
__global__ __launch_bounds__(256) void alpha_kernel(const float* __restrict__ xW,
                                                    const float* __restrict__ a_src,
                                                    const float* __restrict__ a_dst,
                                                    float* __restrict__ aS,
                                                    float* __restrict__ aD, int heads) {
    int v = blockIdx.x, t = threadIdx.x;
    float x = xW[(size_t)v * 256 + t];
    float ps = x * a_src[t];
    float pd = x * a_dst[t];
#pragma unroll
    for (int d = 32; d; d >>= 1) {
        ps += __shfl_down(ps, d, 64);
        pd += __shfl_down(pd, d, 64);
    }
    int lane = t & 63, wid = t >> 6;
    if (heads == 4) {
        if (lane == 0) { aS[v * 4 + wid] = ps; aD[v * 4 + wid] = pd; }
    } else {
        __shared__ float sp[4], sd[4];
        if (lane == 0) { sp[wid] = ps; sd[wid] = pd; }
        __syncthreads();
        if (t == 0) {
            aS[v] = sp[0] + sp[1] + sp[2] + sp[3];
            aD[v] = sd[0] + sd[1] + sd[2] + sd[3];
        }
    }
}

// ---------------------------------------------------------------------------
// Wave-per-node segment softmax + aggregation. Lane l owns features [4l,4l+4).
// HEADS=4: lanes (h*16+q) compute weights for edge-chunk slot q, head h
//          (16 edges/chunk). HEADS=1: lane q computes edge slot q (64/chunk).
// Each gather iteration: whole wave loads one full 1KB xW row (dwordx4/lane).
// Weights computed once per (edge,head); broadcast via shfl. No LDS, no syncs.
// ---------------------------------------------------------------------------
template <int HEADS, bool ELU>
__global__ __launch_bounds__(256) void gat_aggregate_wave(
        const float* __restrict__ xW, const float* __restrict__ aS,
        const float* __restrict__ aD, const int* __restrict__ row_ptr,
        const int* __restrict__ col_src, const float* __restrict__ bias,
        float* __restrict__ out) {
    const int wid  = threadIdx.x >> 6;
    const int lane = threadIdx.x & 63;
    const int v = blockIdx.x * 4 + wid;
    if (v >= N_NODES) return;

    constexpr int CH = 64 / HEADS;                    // edges per chunk
    const int h = (HEADS == 4) ? (lane >> 4) : 0;     // my head
    const int q = (HEADS == 4) ? (lane & 15) : lane;  // my edge slot

    const int beg = row_ptr[v], end = row_ptr[v + 1];
    const float adv = aD[v * HEADS + h];

    // ---- pass A: per-head segment max ----
    float m = -3.4e38f;
    for (int j0 = beg; j0 < end; j0 += CH) {
        int j = j0 + q;
        if (j < end) {
            int s = col_src[j];
            float e = aS[s * HEADS + h] + adv;
            e = (e > 0.f) ? e : SLOPE * e;
            m = fmaxf(m, e);
        }
    }
#pragma unroll
    for (int d = 1; d < CH; d <<= 1) m = fmaxf(m, __shfl_xor(m, d, 64));

    // ---- pass B: weights + gather ----
    float4 acc = make_float4(0.f, 0.f, 0.f, 0.f);
    float z = 0.f;
    for (int j0 = beg; j0 < end; j0 += CH) {
        int cnt = min(CH, end - j0);
        int s = 0;
        float wgt = 0.f;
        if (q < cnt) {
            s = col_src[j0 + q];
            float e = aS[s * HEADS + h] + adv;
            e = (e > 0.f) ? e : SLOPE * e;
            wgt = __expf(e - m);
        }
        z += wgt;
        for (int jj = 0; jj < cnt; ++jj) {
            int bl = (HEADS == 4) ? ((lane & 48) | jj) : jj;
            int   sj = __shfl(s, bl, 64);
            float wj = __shfl(wgt, bl, 64);
            const float4 row = *(const float4*)(xW + ((size_t)sj << 8) + (lane << 2));
            acc.x = fmaf(wj, row.x, acc.x);
            acc.y = fmaf(wj, row.y, acc.y);
            acc.z = fmaf(wj, row.z, acc.z);
            acc.w = fmaf(wj, row.w, acc.w);
        }
    }
#pragma unroll
    for (int d = 1; d < CH; d <<= 1) z += __shfl_xor(z, d, 64);

    float rz = 1.f / z;
    float4 bv = *(const float4*)(bias + (lane << 2));
    float4 o;
    o.x = acc.x * rz + bv.x;
    o.y = acc.y * rz + bv.y;
    o.z = acc.z * rz + bv.z;
    o.w = acc.w * rz + bv.w;
    if (ELU) {
        o.x = (o.x > 0.f) ? o.x : expm1f(o.x);
        o.y = (o.y > 0.f) ? o.y : expm1f(o.y);
        o.z = (o.z > 0.f) ? o.z : expm1f(o.z);
        o.w = (o.w > 0.f) ? o.w : expm1f(o.w);
    }
    *(float4*)(out + ((size_t)v << 8) + (lane << 2)) = o;
}

// ---------------------------------------------------------------------------
extern "C" void kernel_launch(void* const* d_in, const int* in_sizes, int n_in,
                              void* d_out, int out_size, void* d_ws, size_t ws_size,
                              hipStream_t stream) {
    const float* x   = (const float*)d_in[0];
    const int*   ei  = (const int*)d_in[1];
    const float* W1  = (const float*)d_in[2];
    const float* as1 = (const float*)d_in[3];
    const float* ad1 = (const float*)d_in[4];
    const float* b1  = (const float*)d_in[5];
    const float* W2  = (const float*)d_in[6];
    const float* as2 = (const float*)d_in[7];
    const float* ad2 = (const float*)d_in[8];
    const float* b2  = (const float*)d_in[9];
    float* out = (float*)d_out;

    const int* src = ei;
    const int* dst = ei + N_EDGES;

    char* w = (char*)d_ws;
    float* xW = (float*)w;  w += (size_t)N_NODES * 256 * 4;
    float* h  = (float*)w;  w += (size_t)N_NODES * 256 * 4;
    float* aS = (float*)w;  w += (size_t)N_NODES * 4 * 4;
    float* aD = (float*)w;  w += (size_t)N_NODES * 4 * 4;
    int* row_ptr = (int*)w; w += (((size_t)(N_NODES + 1) * 4 + 255) / 256) * 256;
    int* counts  = (int*)w; w += (((size_t)N_NODES * 4 + 255) / 256) * 256;
    int* cursor  = (int*)w; w += (((size_t)N_NODES * 4 + 255) / 256) * 256;
    int* partial = (int*)w; w += (((size_t)N_NODES * 4 + 255) / 256) * 256;
    int* bsums   = (int*)w; w += 256;
    int* col_src = (int*)w; w += (size_t)ETOT * 4;

    int nb = (N_NODES + 1023) / 1024;

    init_counts<<<(N_NODES + 255) / 256, 256, 0, stream>>>(counts);
    count_edges<<<(N_EDGES + 255) / 256, 256, 0, stream>>>(dst, counts);
    scan1<<<nb, 256, 0, stream>>>(counts, partial, bsums);
    scan2<<<1, 64, 0, stream>>>(bsums, nb);
    scan3<<<nb, 256, 0, stream>>>(partial, bsums, row_ptr, cursor);
    scatter_edges<<<(ETOT + 255) / 256, 256, 0, stream>>>(src, dst, cursor, col_src);

    dim3 ggrid(4, (N_NODES + 63) / 64);
    int agg_blocks = (N_NODES + 3) / 4;

    // --- layer 1 (H=4, C=64) ---
    gemm256<<<ggrid, 256, 0, stream>>>(x, W1, xW, N_NODES);
    alpha_kernel<<<N_NODES, 256, 0, stream>>>(xW, as1, ad1, aS, aD, 4);
    gat_aggregate_wave<4, true><<<agg_blocks, 256, 0, stream>>>(xW, aS, aD, row_ptr, col_src, b1, h);

    // --- layer 2 (H=1, C=256) ---
    gemm256<<<ggrid, 256, 0, stream>>>(h, W2, xW, N_NODES);
    alpha_kernel<<<N_NODES, 256, 0, stream>>>(xW, as2, ad2, aS, aD, 1);
    gat_aggregate_wave<1, false><<<agg_blocks, 256, 0, stream>>>(xW, aS, aD, row_ptr, col_src, b2, out);
}

// Round 3
// 458.559 us; speedup vs baseline: 1.7251x; 1.2953x over previous
//
#include <hip/hip_runtime.h>
#include <hip/hip_bf16.h>
#include <math.h>

#define N_NODES 50000
#define N_EDGES 800000
#define ETOT    (N_EDGES + N_NODES)
#define FDIM    256
#define SLOPE   0.2f

typedef __bf16 bf16x8 __attribute__((ext_vector_type(8)));
typedef float  f32x4  __attribute__((ext_vector_type(4)));

// ---------------------------------------------------------------------------
// CSR build (dst-indexed, includes self loops). Rebuilt every call (no state).
// ---------------------------------------------------------------------------
__global__ void init_counts(int* __restrict__ counts) {
    int i = blockIdx.x * blockDim.x + threadIdx.x;
    if (i < N_NODES) counts[i] = 1;
}

__global__ void count_edges(const int* __restrict__ dst, int* __restrict__ counts) {
    int i = blockIdx.x * blockDim.x + threadIdx.x;
    if (i < N_EDGES) atomicAdd(&counts[dst[i]], 1);
}

__global__ void scan1(const int* __restrict__ counts, int* __restrict__ partial,
                      int* __restrict__ blockSums) {
    __shared__ int wsum[4];
    int b = blockIdx.x, t = threadIdx.x;
    int base = b * 1024;
    int i0 = base + t * 4;
    int v[4];
#pragma unroll
    for (int u = 0; u < 4; u++) { int i = i0 + u; v[u] = (i < N_NODES) ? counts[i] : 0; }
    v[1] += v[0]; v[2] += v[1]; v[3] += v[2];
    int lane = t & 63, wid = t >> 6;
    int incl = v[3];
#pragma unroll
    for (int d = 1; d < 64; d <<= 1) {
        int o = __shfl_up(incl, d, 64);
        if (lane >= d) incl += o;
    }
    if (lane == 63) wsum[wid] = incl;
    __syncthreads();
    int woff = 0;
#pragma unroll
    for (int w = 0; w < 4; w++) if (w < wid) woff += wsum[w];
    int texcl = woff + incl - v[3];
#pragma unroll
    for (int u = 0; u < 4; u++) { int i = i0 + u; if (i < N_NODES) partial[i] = texcl + v[u]; }
    if (t == 255) blockSums[b] = woff + incl;
}

__global__ void scan2(int* __restrict__ blockSums, int nb) {
    int t = threadIdx.x;
    int v = (t < nb) ? blockSums[t] : 0;
    int incl = v;
#pragma unroll
    for (int d = 1; d < 64; d <<= 1) {
        int o = __shfl_up(incl, d, 64);
        if (t >= d) incl += o;
    }
    if (t < nb) blockSums[t] = incl - v;
}

__global__ void scan3(const int* __restrict__ partial, const int* __restrict__ blockOffs,
                      int* __restrict__ row_ptr, int* __restrict__ cursor) {
    int b = blockIdx.x, t = threadIdx.x;
    int base = b * 1024;
    int off = blockOffs[b];
#pragma unroll
    for (int u = 0; u < 4; u++) {
        int i = base + t + u * 256;
        if (i < N_NODES) {
            row_ptr[i + 1] = off + partial[i];
            cursor[i]      = off + ((i == base) ? 0 : partial[i - 1]);
        }
    }
    if (b == 0 && t == 0) row_ptr[0] = 0;
}

__global__ void scatter_edges(const int* __restrict__ src, const int* __restrict__ dst,
                              int* __restrict__ cursor, int* __restrict__ col_src) {
    int i = blockIdx.x * blockDim.x + threadIdx.x;
    if (i >= ETOT) return;
    int s, d;
    if (i < N_EDGES) { s = src[i]; d = dst[i]; }
    else             { s = i - N_EDGES; d = s; }
    int p = atomicAdd(&cursor[d], 1);
    col_src[p] = s;
}

// ---------------------------------------------------------------------------
// Pre-split W into bf16 hi/lo, transposed: Wt[col][k] = W[k][col].
// ---------------------------------------------------------------------------
__global__ void split_w(const float* __restrict__ W, __bf16* __restrict__ Wth,
                        __bf16* __restrict__ Wtl) {
    int i = blockIdx.x * 256 + threadIdx.x;   // 65536 elements
    int k = i >> 8, c = i & 255;
    float v = W[i];
    __bf16 h = (__bf16)v;
    Wth[(c << 8) + k] = h;
    Wtl[(c << 8) + k] = (__bf16)(v - (float)h);
}

// ---------------------------------------------------------------------------
// Split-bf16 MFMA GEMM: C[M,256] = A[M,256] @ W[256,256], fp32-equivalent via
// hi*hi + hi*lo + lo*hi. Tile 64x256 per block (full row width), 4 waves:
// wave w owns cols [64w,64w+64). Fused alpha epilogue: aS/aD row dots.
// Fragment layout (16x16x32 bf16): A lane l: row=l&15, k=8*(l>>4)+j.
//                                  B lane l: col=l&15, k=8*(l>>4)+j.
//                                  C lane l reg r: row=4*(l>>4)+r, col=l&15.
// ---------------------------------------------------------------------------
template <int HEADS>
__global__ __launch_bounds__(256) void gemm_mfma(
        const float* __restrict__ A, const __bf16* __restrict__ Bth,
        const __bf16* __restrict__ Btl, float* __restrict__ C,
        const float* __restrict__ avS, const float* __restrict__ avD,
        float* __restrict__ aS, float* __restrict__ aD, int M) {
    constexpr int LDA = 40;                    // padded k-stride (bf16 elems)
    __shared__ __bf16 Ah[64 * LDA];
    __shared__ __bf16 Al[64 * LDA];
    __shared__ float sred[2][64][4];           // [s|d][row][wave]

    const int t = threadIdx.x;
    const int w = t >> 6, l = t & 63;
    const int q = l >> 4, c16 = l & 15;
    const int row0 = blockIdx.x * 64;

    const int ar = t >> 2, ak = (t & 3) << 3;  // staging: row, k-offset (8 floats)
    const bool arow_ok = (row0 + ar) < M;
    const float* Arow = A + (size_t)(row0 + ar) * 256 + ak;

    f32x4 acc[4][4];
#pragma unroll
    for (int i = 0; i < 4; i++)
#pragma unroll
        for (int j = 0; j < 4; j++) acc[i][j] = (f32x4){0.f, 0.f, 0.f, 0.f};

    for (int k0 = 0; k0 < 256; k0 += 32) {
        // ---- stage A tile 64x32 fp32 -> bf16 hi/lo in LDS ----
        float4 v0 = make_float4(0.f, 0.f, 0.f, 0.f), v1 = v0;
        if (arow_ok) {
            v0 = *(const float4*)(Arow + k0);
            v1 = *(const float4*)(Arow + k0 + 4);
        }
        float vv[8] = {v0.x, v0.y, v0.z, v0.w, v1.x, v1.y, v1.z, v1.w};
        bf16x8 hv, lv;
#pragma unroll
        for (int j = 0; j < 8; j++) {
            __bf16 hb = (__bf16)vv[j];
            hv[j] = hb;
            lv[j] = (__bf16)(vv[j] - (float)hb);
        }
        *(bf16x8*)(&Ah[ar * LDA + ak]) = hv;
        *(bf16x8*)(&Al[ar * LDA + ak]) = lv;
        __syncthreads();

        // ---- B fragments direct from global (L2-resident, pre-transposed) ----
        bf16x8 bh[4], bl[4];
#pragma unroll
        for (int nb = 0; nb < 4; nb++) {
            int col = (w << 6) + (nb << 4) + c16;
            size_t boff = ((size_t)col << 8) + k0 + (q << 3);
            bh[nb] = *(const bf16x8*)(Bth + boff);
            bl[nb] = *(const bf16x8*)(Btl + boff);
        }
        // ---- A fragments from LDS ----
        bf16x8 ah[4], alo[4];
#pragma unroll
        for (int mb = 0; mb < 4; mb++) {
            int off = (c16 + (mb << 4)) * LDA + (q << 3);
            ah[mb]  = *(const bf16x8*)(&Ah[off]);
            alo[mb] = *(const bf16x8*)(&Al[off]);
        }
#pragma unroll
        for (int mb = 0; mb < 4; mb++)
#pragma unroll
            for (int nb = 0; nb < 4; nb++) {
                acc[mb][nb] = __builtin_amdgcn_mfma_f32_16x16x32_bf16(ah[mb],  bh[nb], acc[mb][nb], 0, 0, 0);
                acc[mb][nb] = __builtin_amdgcn_mfma_f32_16x16x32_bf16(ah[mb],  bl[nb], acc[mb][nb], 0, 0, 0);
                acc[mb][nb] = __builtin_amdgcn_mfma_f32_16x16x32_bf16(alo[mb], bh[nb], acc[mb][nb], 0, 0, 0);
            }
        __syncthreads();
    }

    // ---- epilogue: store C + fused alpha row-dots ----
#pragma unroll
    for (int mb = 0; mb < 4; mb++) {
#pragma unroll
        for (int r = 0; r < 4; r++) {
            int row = (mb << 4) + (q << 2) + r;
            int grow = row0 + row;
            float s = 0.f, d = 0.f;
#pragma unroll
            for (int nb = 0; nb < 4; nb++) {
                int col = (w << 6) + (nb << 4) + c16;
                float val = acc[mb][nb][r];
                s = fmaf(val, avS[col], s);
                d = fmaf(val, avD[col], d);
                if (grow < M) C[(size_t)grow * 256 + col] = val;
            }
#pragma unroll
            for (int dd = 1; dd < 16; dd <<= 1) {
                s += __shfl_xor(s, dd, 64);
                d += __shfl_xor(d, dd, 64);
            }
            if (c16 == 0) { sred[0][row][w] = s; sred[1][row][w] = d; }
        }
    }
    __syncthreads();
    if (HEADS == 4) {
        int row = t >> 2, wv = t & 3;
        int v = row0 + row;
        if (v < M) { aS[v * 4 + wv] = sred[0][row][wv]; aD[v * 4 + wv] = sred[1][row][wv]; }
    } else {
        if (t < 64) {
            int v = row0 + t;
            if (v < M) {
                aS[v] = sred[0][t][0] + sred[0][t][1] + sred[0][t][2] + sred[0][t][3];
                aD[v] = sred[1][t][0] + sred[1][t][1] + sred[1][t][2] + sred[1][t][3];
            }
        }
    }
}

// ---------------------------------------------------------------------------
// Wave-per-node segment softmax + aggregation (unchanged from round 1).
// ---------------------------------------------------------------------------
template <int HEADS, bool ELU>
__global__ __launch_bounds__(256) void gat_aggregate_wave(
        const float* __restrict__ xW, const float* __restrict__ aS,
        const float* __restrict__ aD, const int* __restrict__ row_ptr,
        const int* __restrict__ col_src, const float* __restrict__ bias,
        float* __restrict__ out) {
    const int wid  = threadIdx.x >> 6;
    const int lane = threadIdx.x & 63;
    const int v = blockIdx.x * 4 + wid;
    if (v >= N_NODES) return;

    constexpr int CH = 64 / HEADS;
    const int h = (HEADS == 4) ? (lane >> 4) : 0;
    const int q = (HEADS == 4) ? (lane & 15) : lane;

    const int beg = row_ptr[v], end = row_ptr[v + 1];
    const float adv = aD[v * HEADS + h];

    float m = -3.4e38f;
    for (int j0 = beg; j0 < end; j0 += CH) {
        int j = j0 + q;
        if (j < end) {
            int s = col_src[j];
            float e = aS[s * HEADS + h] + adv;
            e = (e > 0.f) ? e : SLOPE * e;
            m = fmaxf(m, e);
        }
    }
#pragma unroll
    for (int d = 1; d < CH; d <<= 1) m = fmaxf(m, __shfl_xor(m, d, 64));

    float4 acc = make_float4(0.f, 0.f, 0.f, 0.f);
    float z = 0.f;
    for (int j0 = beg; j0 < end; j0 += CH) {
        int cnt = min(CH, end - j0);
        int s = 0;
        float wgt = 0.f;
        if (q < cnt) {
            s = col_src[j0 + q];
            float e = aS[s * HEADS + h] + adv;
            e = (e > 0.f) ? e : SLOPE * e;
            wgt = __expf(e - m);
        }
        z += wgt;
        for (int jj = 0; jj < cnt; ++jj) {
            int bl = (HEADS == 4) ? ((lane & 48) | jj) : jj;
            int   sj = __shfl(s, bl, 64);
            float wj = __shfl(wgt, bl, 64);
            const float4 row = *(const float4*)(xW + ((size_t)sj << 8) + (lane << 2));
            acc.x = fmaf(wj, row.x, acc.x);
            acc.y = fmaf(wj, row.y, acc.y);
            acc.z = fmaf(wj, row.z, acc.z);
            acc.w = fmaf(wj, row.w, acc.w);
        }
    }
#pragma unroll
    for (int d = 1; d < CH; d <<= 1) z += __shfl_xor(z, d, 64);

    float rz = 1.f / z;
    float4 bv = *(const float4*)(bias + (lane << 2));
    float4 o;
    o.x = acc.x * rz + bv.x;
    o.y = acc.y * rz + bv.y;
    o.z = acc.z * rz + bv.z;
    o.w = acc.w * rz + bv.w;
    if (ELU) {
        o.x = (o.x > 0.f) ? o.x : expm1f(o.x);
        o.y = (o.y > 0.f) ? o.y : expm1f(o.y);
        o.z = (o.z > 0.f) ? o.z : expm1f(o.z);
        o.w = (o.w > 0.f) ? o.w : expm1f(o.w);
    }
    *(float4*)(out + ((size_t)v << 8) + (lane << 2)) = o;
}

// ---------------------------------------------------------------------------
extern "C" void kernel_launch(void* const* d_in, const int* in_sizes, int n_in,
                              void* d_out, int out_size, void* d_ws, size_t ws_size,
                              hipStream_t stream) {
    const float* x   = (const float*)d_in[0];
    const int*   ei  = (const int*)d_in[1];
    const float* W1  = (const float*)d_in[2];
    const float* as1 = (const float*)d_in[3];
    const float* ad1 = (const float*)d_in[4];
    const float* b1  = (const float*)d_in[5];
    const float* W2  = (const float*)d_in[6];
    const float* as2 = (const float*)d_in[7];
    const float* ad2 = (const float*)d_in[8];
    const float* b2  = (const float*)d_in[9];
    float* out = (float*)d_out;

    const int* src = ei;
    const int* dst = ei + N_EDGES;

    char* w = (char*)d_ws;
    float* xW = (float*)w;  w += (size_t)N_NODES * 256 * 4;
    float* h  = (float*)w;  w += (size_t)N_NODES * 256 * 4;
    float* aS = (float*)w;  w += (size_t)N_NODES * 4 * 4;
    float* aD = (float*)w;  w += (size_t)N_NODES * 4 * 4;
    int* row_ptr = (int*)w; w += (((size_t)(N_NODES + 1) * 4 + 255) / 256) * 256;
    int* counts  = (int*)w; w += (((size_t)N_NODES * 4 + 255) / 256) * 256;
    int* cursor  = (int*)w; w += (((size_t)N_NODES * 4 + 255) / 256) * 256;
    int* partial = (int*)w; w += (((size_t)N_NODES * 4 + 255) / 256) * 256;
    int* bsums   = (int*)w; w += 256;
    int* col_src = (int*)w; w += (size_t)ETOT * 4;
    __bf16* Wth = (__bf16*)w; w += 65536 * 2;
    __bf16* Wtl = (__bf16*)w; w += 65536 * 2;

    int nb = (N_NODES + 1023) / 1024;

    init_counts<<<(N_NODES + 255) / 256, 256, 0, stream>>>(counts);
    count_edges<<<(N_EDGES + 255) / 256, 256, 0, stream>>>(dst, counts);
    scan1<<<nb, 256, 0, stream>>>(counts, partial, bsums);
    scan2<<<1, 64, 0, stream>>>(bsums, nb);
    scan3<<<nb, 256, 0, stream>>>(partial, bsums, row_ptr, cursor);
    scatter_edges<<<(ETOT + 255) / 256, 256, 0, stream>>>(src, dst, cursor, col_src);

    int gemm_blocks = (N_NODES + 63) / 64;   // 782
    int agg_blocks  = (N_NODES + 3) / 4;

    // --- layer 1 (H=4, C=64) ---
    split_w<<<256, 256, 0, stream>>>(W1, Wth, Wtl);
    gemm_mfma<4><<<gemm_blocks, 256, 0, stream>>>(x, Wth, Wtl, xW, as1, ad1, aS, aD, N_NODES);
    gat_aggregate_wave<4, true><<<agg_blocks, 256, 0, stream>>>(xW, aS, aD, row_ptr, col_src, b1, h);

    // --- layer 2 (H=1, C=256) ---
    split_w<<<256, 256, 0, stream>>>(W2, Wth, Wtl);
    gemm_mfma<1><<<gemm_blocks, 256, 0, stream>>>(h, Wth, Wtl, xW, as2, ad2, aS, aD, N_NODES);
    gat_aggregate_wave<1, false><<<agg_blocks, 256, 0, stream>>>(xW, aS, aD, row_ptr, col_src, b2, out);
}